// Round 13
// baseline (370.925 us; speedup 1.0000x reference)
//
#include <hip/hip_runtime.h>
#include <hip/hip_bf16.h>
#include <cstdint>
#include <cstddef>

#define N_NODES 50000
#define N_EDGES 800000
#define IN_CH 64
#define HID_CH 128
#define N_GRAPHS 64

#define NB_SCAN ((N_NODES + 255) / 256)          // 196
#define NB_CNT  ((N_EDGES + 255) / 256)          // 3125
#define NB_GEMM ((N_NODES + 63) / 64)            // 782
#define W_ELEMS (4 * IN_CH * 128 + 4 * HID_CH * 128)  // 98304
#define NB_CONV ((W_ELEMS + 255) / 256)          // 384

typedef short s16x8 __attribute__((ext_vector_type(8)));
typedef float f32x4 __attribute__((ext_vector_type(4)));
typedef float f32x2 __attribute__((ext_vector_type(2)));

__device__ __forceinline__ float bf2f(__hip_bfloat16 v) { return __bfloat162float(v); }
__device__ __forceinline__ float bfbits2f(unsigned hs) {
  union { unsigned u; float f; } v; v.u = hs << 16; return v.f;
}
__device__ __forceinline__ float bfhi2f(unsigned w) {
  union { unsigned u; float f; } v; v.u = w & 0xffff0000u; return v.f;
}
__device__ __forceinline__ short f2bfs(float f) {
  __hip_bfloat16 h = __float2bfloat16(f); return *(short*)&h;
}
__device__ __forceinline__ unsigned short f2bfu(float f) {
  __hip_bfloat16 h = __float2bfloat16(f); return *(unsigned short*)&h;
}
__device__ __forceinline__ int clamp_id(int v) {
  if (v < 0) v = 0;
  if (v >= N_NODES) v = N_NODES - 1;
  return v;
}

// fp8 e4m3 (OCP) pack/unpack via gfx950 HW converters (word-selects are immediates).
__device__ __forceinline__ unsigned char f2fp8(float v) {
  return (unsigned char)(__builtin_amdgcn_cvt_pk_fp8_f32(v, v, 0, false) & 0xff);
}
template<bool HI>
__device__ __forceinline__ f32x2 fp8pair(unsigned w) {
  return __builtin_amdgcn_cvt_pk_f32_fp8(w, HI);
}

// ---------------- A: zero workspace + weight canonicalization ----------------
// W logical [KD][128] fp32 -> image WT[((k>>3)*128 + c)*8 + (k&7)] bf16
__global__ __launch_bounds__(256)
void prep(const float* __restrict__ w1q, const float* __restrict__ w1k,
          const float* __restrict__ w1v, const float* __restrict__ w1s,
          const float* __restrict__ w2q, const float* __restrict__ w2k,
          const float* __restrict__ w2v, const float* __restrict__ w2s,
          __hip_bfloat16* d1q, __hip_bfloat16* d1k, __hip_bfloat16* d1v, __hip_bfloat16* d1s,
          __hip_bfloat16* d2q, __hip_bfloat16* d2k, __hip_bfloat16* d2v, __hip_bfloat16* d2s,
          int* cnt, int* tmp, float* pooled)
{
  int bx = blockIdx.x;
  if (bx < NB_SCAN) {
    int i = bx * 256 + threadIdx.x;
    if (i < N_NODES) { cnt[i] = 0; tmp[i] = 0; }
    if (i < N_GRAPHS * HID_CH) pooled[i] = 0.f;
    return;
  }
  int j = (bx - NB_SCAN) * 256 + threadIdx.x;
  if (j >= W_ELEMS) return;
  const float* S[8] = {w1q, w1k, w1v, w1s, w2q, w2k, w2v, w2s};
  __hip_bfloat16* D[8] = {d1q, d1k, d1v, d1s, d2q, d2k, d2v, d2s};
  int m, r;
  if (j < 4 * IN_CH * 128) { m = j >> 13; r = j & 8191; }
  else { int jj = j - 4 * IN_CH * 128; m = 4 + (jj >> 14); r = jj & 16383; }
  int k = r >> 7, c = r & 127;
  D[m][(((k >> 3) * 128 + c) << 3) + (k & 7)] = __float2bfloat16(S[m][r]);
}

// ---------------- shared gemm body (LDS-B, register-pipelined staging) ----------------
// Outputs: mat0=Q (bf16, row 128), mat1=K -> KV8 row byte [0..128), mat2=V -> KV8 [128..256),
// mat3=S (bf16, row 128). KV8 row = 256 bytes, fp8 e4m3.
// Staging for mat m+1 is global-loaded into registers while mat m computes, so the
// per-mat critical path is ds_write -> barrier -> ds_read/MFMA -> barrier (no global latency).
// So may alias X (in-place per-row: A-frags register-resident before stores).
template<int KD, int XF32>
__device__ __forceinline__ void gemm_body(
    int bg, const void* X,
    const short* __restrict__ WTq, const short* __restrict__ WTk,
    const short* __restrict__ WTv, const short* __restrict__ WTs,
    const float* __restrict__ bq, const float* __restrict__ bk,
    const float* __restrict__ bv, const float* __restrict__ bs,
    short* Qo, unsigned char* KV8, short* So, short* lds)
{
  constexpr int KT = KD / 32;
  constexpr int PER = (KD * 16) / 256;   // uint4 chunks per thread (4 or 8)
  const int tid  = threadIdx.x;
  const int wid  = tid >> 6;
  const int lane = tid & 63;
  const int quad = lane >> 4;
  const int mm   = lane & 15;
  const int rt   = wid & 1;
  const int ch   = wid >> 1;
  const int rowbase = bg * 64 + rt * 32;

  s16x8 afrag[2][KT];
  #pragma unroll
  for (int t = 0; t < 2; ++t) {
    const int arow = rowbase + t * 16 + mm;
    if (arow < N_NODES) {
      if (XF32) {
        const float* xp = (const float*)X + (size_t)arow * KD;
        #pragma unroll
        for (int kt = 0; kt < KT; ++kt) {
          const float4* p = (const float4*)(xp + kt * 32 + quad * 8);
          float4 a = p[0], b = p[1];
          s16x8 fr;
          fr[0] = f2bfs(a.x); fr[1] = f2bfs(a.y); fr[2] = f2bfs(a.z); fr[3] = f2bfs(a.w);
          fr[4] = f2bfs(b.x); fr[5] = f2bfs(b.y); fr[6] = f2bfs(b.z); fr[7] = f2bfs(b.w);
          afrag[t][kt] = fr;
        }
      } else {
        const short* xp = (const short*)X + (size_t)arow * KD;
        #pragma unroll
        for (int kt = 0; kt < KT; ++kt)
          afrag[t][kt] = *(const s16x8*)(xp + kt * 32 + quad * 8);
      }
    } else {
      #pragma unroll
      for (int kt = 0; kt < KT; ++kt)
        afrag[t][kt] = (s16x8){0,0,0,0,0,0,0,0};
    }
  }

  const short* wts[4] = {WTq, WTk, WTv, WTs};
  const float* bias[4] = {bq, bk, bv, bs};

  // preload mat 0 staging into registers
  uint4 stg[PER];
  #pragma unroll
  for (int i = 0; i < PER; ++i)
    stg[i] = ((const uint4*)wts[0])[tid + i * 256];

  #pragma unroll
  for (int mat = 0; mat < 4; ++mat) {
    __syncthreads();                       // prev mat's readers done; LDS free
    {
      uint4* dst = (uint4*)lds;
      #pragma unroll
      for (int i = 0; i < PER; ++i)
        dst[tid + i * 256] = stg[i];
    }
    if (mat < 3) {                         // prefetch next mat during this mat's compute
      #pragma unroll
      for (int i = 0; i < PER; ++i)
        stg[i] = ((const uint4*)wts[mat + 1])[tid + i * 256];
    }
    __syncthreads();

    f32x4 acc[4][2];
    #pragma unroll
    for (int c4 = 0; c4 < 4; ++c4) {
      float b = bias[mat][ch * 64 + c4 * 16 + mm];
      f32x4 av = {b, b, b, b};
      acc[c4][0] = av; acc[c4][1] = av;
    }
    #pragma unroll
    for (int kt = 0; kt < KT; ++kt) {
      #pragma unroll
      for (int c4 = 0; c4 < 4; ++c4) {
        s16x8 bfrag = *(const s16x8*)(lds + ((((kt * 4 + quad) << 7) + ch * 64 + c4 * 16 + mm) << 3));
        acc[c4][0] = __builtin_amdgcn_mfma_f32_16x16x32_bf16(afrag[0][kt], bfrag, acc[c4][0], 0, 0, 0);
        acc[c4][1] = __builtin_amdgcn_mfma_f32_16x16x32_bf16(afrag[1][kt], bfrag, acc[c4][1], 0, 0, 0);
      }
    }
    if (mat == 1 || mat == 2) {
      unsigned char* O8 = KV8 + ((mat == 1) ? 0 : 128);
      #pragma unroll
      for (int c4 = 0; c4 < 4; ++c4) {
        const int col = ch * 64 + c4 * 16 + mm;
        #pragma unroll
        for (int t = 0; t < 2; ++t) {
          #pragma unroll
          for (int r = 0; r < 4; ++r) {
            int row = rowbase + t * 16 + quad * 4 + r;
            if (row < N_NODES)
              O8[(size_t)row * 256 + col] = f2fp8(acc[c4][t][r]);
          }
        }
      }
    } else {
      short* O = (mat == 0) ? Qo : So;
      #pragma unroll
      for (int c4 = 0; c4 < 4; ++c4) {
        const int col = ch * 64 + c4 * 16 + mm;
        #pragma unroll
        for (int t = 0; t < 2; ++t) {
          #pragma unroll
          for (int r = 0; r < 4; ++r) {
            int row = rowbase + t * 16 + quad * 4 + r;
            if (row < N_NODES)
              ((__hip_bfloat16*)O)[(size_t)row * 128 + col] = __float2bfloat16(acc[c4][t][r]);
          }
        }
      }
    }
  }
}

// ---------------- B: layer-1 gemm FIRST + count_deg after (LPT scheduling) ----------------
__global__ __launch_bounds__(256)
void count_gemm1(const int* __restrict__ ei, int* __restrict__ cnt,
                 const float* __restrict__ X,
                 const short* __restrict__ w1q, const short* __restrict__ w1k,
                 const short* __restrict__ w1v, const short* __restrict__ w1s,
                 const float* __restrict__ b1q, const float* __restrict__ b1k,
                 const float* __restrict__ b1v, const float* __restrict__ b1s,
                 short* Qb, unsigned char* KV8, short* Sb)
{
  __shared__ short lds[IN_CH * 128];   // 16 KB
  int bx = blockIdx.x;
  if (bx >= NB_GEMM) {
    int e = (bx - NB_GEMM) * 256 + threadIdx.x;
    if (e < N_EDGES) atomicAdd(&cnt[clamp_id(ei[N_EDGES + e])], 1);
    return;
  }
  gemm_body<IN_CH, 1>(bx, X, w1q, w1k, w1v, w1s, b1q, b1k, b1v, b1s,
                      Qb, KV8, Sb, lds);
}

// ---------------- C1/C2: scan ----------------
__global__ __launch_bounds__(256)
void scan1(const int* __restrict__ cnt, int* __restrict__ offs, int* __restrict__ bsum) {
  __shared__ int wsum[4];
  int t = threadIdx.x, lane = t & 63, w = t >> 6;
  int i = blockIdx.x * 256 + t;
  int v = (i < N_NODES) ? cnt[i] : 0;
  int x = v;
  #pragma unroll
  for (int o = 1; o < 64; o <<= 1) { int y = __shfl_up(x, o, 64); if (lane >= o) x += y; }
  if (lane == 63) wsum[w] = x;
  __syncthreads();
  if (t == 0) {
    int run = 0;
    #pragma unroll
    for (int k = 0; k < 4; ++k) { int tv = wsum[k]; wsum[k] = run; run += tv; }
    bsum[blockIdx.x] = run;
  }
  __syncthreads();
  if (i <= N_NODES) offs[i] = wsum[w] + x - v;   // block-local exclusive prefix
}

__global__ __launch_bounds__(256)
void scan2(int* __restrict__ bsum) {
  __shared__ int wsum[4];
  int t = threadIdx.x, lane = t & 63, w = t >> 6;
  int v = (t < NB_SCAN) ? bsum[t] : 0;
  int x = v;
  #pragma unroll
  for (int o = 1; o < 64; o <<= 1) { int y = __shfl_up(x, o, 64); if (lane >= o) x += y; }
  if (lane == 63) wsum[w] = x;
  __syncthreads();
  if (t == 0) {
    int run = 0;
    #pragma unroll
    for (int k = 0; k < 4; ++k) { int tv = wsum[k]; wsum[k] = run; run += tv; }
  }
  __syncthreads();
  if (t < NB_SCAN) bsum[t] = wsum[w] + x - v;    // exclusive prefix of block sums
}

// ---------------- D: scatter (global offset = offs[dst] + bsum[dst>>8]) ----------------
__global__ void scatter_edges(const int* __restrict__ ei, const int* __restrict__ offs,
                              const int* __restrict__ bsum,
                              int* __restrict__ tmp, int* __restrict__ ssrc) {
  int e = blockIdx.x * blockDim.x + threadIdx.x;
  if (e < N_EDGES) {
    int src = clamp_id(ei[e]);
    int dst = clamp_id(ei[N_EDGES + e]);
    int pos = offs[dst] + bsum[dst >> 8] + atomicAdd(&tmp[dst], 1);
    ssrc[pos] = src;
  }
}

// ---------------- attention (fp8 K/V, interleaved 256B rows) ----------------
// 1 wave per dst (4 dsts/block); 4 edge slots x 16 channel-lanes; quad=head.
// No-max softmax in exp2 domain; 1-deep K/V register prefetch.
// H may alias S (in-place per dst row).
__global__ __launch_bounds__(256)
void attn_kernel(const unsigned short* __restrict__ Q, const unsigned char* __restrict__ KV8,
                 const unsigned short* S,
                 const int* __restrict__ offs, const int* __restrict__ bsum,
                 const int* __restrict__ ssrc, unsigned short* H)
{
  const int dst = blockIdx.x * 4 + (threadIdx.x >> 6);
  if (dst >= N_NODES) return;               // wave-uniform
  const int lane = threadIdx.x & 63;
  const int sub  = lane >> 4;
  const int cl   = lane & 15;

  const float qs = 0.17677669529663687f * 1.4426950408889634f;  // 1/sqrt(32)*log2(e)
  uint4 qw = *(const uint4*)(Q + (size_t)dst * 128 + cl * 8);
  float q[8], a[8];
  #pragma unroll
  for (int i = 0; i < 4; ++i) {
    unsigned w = ((unsigned*)&qw)[i];
    q[2 * i]     = bfbits2f(w & 0xffffu) * qs;
    q[2 * i + 1] = bfhi2f(w) * qs;
    a[2 * i] = 0.f; a[2 * i + 1] = 0.f;
  }
  float s = 0.f;

  const int e0 = offs[dst] + bsum[dst >> 8];
  const int e1 = offs[dst + 1] + bsum[(dst + 1) >> 8];
  const int iters = (e1 - e0 + 3) >> 2;

  if (iters > 0) {
    int e = e0 + sub;
    bool have = (e < e1);
    int src = have ? ssrc[e] : ssrc[e0];
    float ph = have ? 1.f : 0.f;
    const unsigned char* kvp = KV8 + (size_t)src * 256 + cl * 8;
    uint2 kw = *(const uint2*)(kvp);
    uint2 vw = *(const uint2*)(kvp + 128);

    for (int it = 0; it < iters; ++it) {
      uint2 kwn, vwn;
      int en = e + 4;
      bool haven = (en < e1);
      float phn = haven ? 1.f : 0.f;
      if (it + 1 < iters) {                 // wave-uniform
        int srcn = haven ? ssrc[en] : ssrc[e0];
        const unsigned char* kvn = KV8 + (size_t)srcn * 256 + cl * 8;
        kwn = *(const uint2*)(kvn);
        vwn = *(const uint2*)(kvn + 128);
      } else {
        kwn = kw; vwn = vw;
      }
      f32x2 k0 = fp8pair<false>(kw.x), k1 = fp8pair<true>(kw.x);
      f32x2 k2 = fp8pair<false>(kw.y), k3 = fp8pair<true>(kw.y);
      float d = q[0] * k0.x + q[1] * k0.y + q[2] * k1.x + q[3] * k1.y
              + q[4] * k2.x + q[5] * k2.y + q[6] * k3.x + q[7] * k3.y;
      d += __shfl_xor(d, 1, 64);
      d += __shfl_xor(d, 2, 64);
      float p = exp2f(d) * ph;
      s += p;
      f32x2 v0 = fp8pair<false>(vw.x), v1 = fp8pair<true>(vw.x);
      f32x2 v2 = fp8pair<false>(vw.y), v3 = fp8pair<true>(vw.y);
      a[0] += p * v0.x; a[1] += p * v0.y;
      a[2] += p * v1.x; a[3] += p * v1.y;
      a[4] += p * v2.x; a[5] += p * v2.y;
      a[6] += p * v3.x; a[7] += p * v3.y;
      kw = kwn; vw = vwn; ph = phn; e = en;
    }
  }

  s += __shfl_xor(s, 16, 64);
  s += __shfl_xor(s, 32, 64);
  #pragma unroll
  for (int i = 0; i < 8; ++i) {
    a[i] += __shfl_xor(a[i], 16, 64);
    a[i] += __shfl_xor(a[i], 32, 64);
  }
  const float inv = (s > 0.f) ? (1.0f / s) : 0.f;

  if (sub == 0) {
    uint4 sw = *(const uint4*)(S + (size_t)dst * 128 + cl * 8);
    uint4 ow;
    #pragma unroll
    for (int i = 0; i < 4; ++i) {
      unsigned w = ((unsigned*)&sw)[i];
      float o0 = fmaxf(a[2 * i] * inv     + bfbits2f(w & 0xffffu), 0.f);
      float o1 = fmaxf(a[2 * i + 1] * inv + bfhi2f(w), 0.f);
      ((unsigned*)&ow)[i] = (unsigned)f2bfu(o0) | ((unsigned)f2bfu(o1) << 16);
    }
    *(uint4*)(H + (size_t)dst * 128 + cl * 8) = ow;
  }
}

// ---------------- F: layer-2 gemm ----------------
__global__ __launch_bounds__(256)
void gemm2(const short* __restrict__ X,
           const short* __restrict__ w2q, const short* __restrict__ w2k,
           const short* __restrict__ w2v, const short* __restrict__ w2s,
           const float* __restrict__ b2q, const float* __restrict__ b2k,
           const float* __restrict__ b2v, const float* __restrict__ b2s,
           short* Qb, unsigned char* KV8, short* Sb)
{
  __shared__ short lds[HID_CH * 128];  // 32 KB
  gemm_body<HID_CH, 0>(blockIdx.x, X, w2q, w2k, w2v, w2s, b2q, b2k, b2v, b2s,
                       Qb, KV8, Sb, lds);
}

// ---------------- pooling (R6-verified: 16 partials/graph, few atomics) ----------------
__device__ __forceinline__ int lower_bound_i(const int* __restrict__ b, int n, int val) {
  int lo = 0, hi = n;
  while (lo < hi) { int mid = (lo + hi) >> 1; if (b[mid] < val) lo = mid + 1; else hi = mid; }
  return lo;
}

__global__ __launch_bounds__(128)
void pool_partial(const __hip_bfloat16* __restrict__ H, const int* __restrict__ batch,
                  float* __restrict__ pooled)
{
  const int g = blockIdx.x >> 4, p = blockIdx.x & 15, t = threadIdx.x;
  const int s = lower_bound_i(batch, N_NODES, g);
  const int e = lower_bound_i(batch, N_NODES, g + 1);
  const int len = e - s;
  if (len <= 0) return;
  const int chunk = (len + 15) >> 4;
  const int a = s + p * chunk;
  const int b = min(a + chunk, e);
  if (a >= b) return;
  float sum = 0.f;
  for (int i = a; i < b; ++i) sum += bf2f(H[(size_t)i * 128 + t]);
  atomicAdd(&pooled[g * 128 + t], sum);
}

__global__ __launch_bounds__(128)
void pool_final(const float* __restrict__ pooled, const int* __restrict__ batch,
                const float* __restrict__ Wl, const float* __restrict__ bl,
                float* __restrict__ out)
{
  const int g = blockIdx.x, t = threadIdx.x;
  __shared__ float r0[128], r1[128];
  const int s = lower_bound_i(batch, N_NODES, g);
  const int e = lower_bound_i(batch, N_NODES, g + 1);
  const float inv = 1.0f / (float)max(e - s, 1);
  const float pc = pooled[g * 128 + t] * inv;
  r0[t] = pc * Wl[t * 2 + 0];
  r1[t] = pc * Wl[t * 2 + 1];
  __syncthreads();
  for (int o = 64; o > 0; o >>= 1) {
    if (t < o) { r0[t] += r0[t + o]; r1[t] += r1[t + o]; }
    __syncthreads();
  }
  if (t == 0) {
    out[g * 2 + 0] = r0[0] + bl[0];
    out[g * 2 + 1] = r1[0] + bl[1];
  }
}

// ---------------- launch ----------------

extern "C" void kernel_launch(void* const* d_in, const int* in_sizes, int n_in,
                              void* d_out, int out_size, void* d_ws, size_t ws_size,
                              hipStream_t stream) {
  uintptr_t base = (uintptr_t)d_ws;
  auto take = [&](size_t bytes) -> uintptr_t {
    uintptr_t p = base;
    base += (bytes + 255) & ~(size_t)255;
    return p;
  };

  int*   cnt    = (int*)take((size_t)N_NODES * 4);
  int*   tmp    = (int*)take((size_t)N_NODES * 4);
  int*   offs   = (int*)take((size_t)(N_NODES + 1) * 4);
  int*   bsum   = (int*)take((size_t)NB_SCAN * 4);
  int*   ssrc   = (int*)take((size_t)N_EDGES * 4);
  short* Qb     = (short*)take((size_t)N_NODES * 128 * 2);
  unsigned char* KV8 = (unsigned char*)take((size_t)N_NODES * 256);  // fp8 [K|V] rows
  short* Sb     = (short*)take((size_t)N_NODES * 128 * 2);  // S / H / layer-2 X (in-place)
  short* wt1q   = (short*)take((size_t)IN_CH * 128 * 2);
  short* wt1k   = (short*)take((size_t)IN_CH * 128 * 2);
  short* wt1v   = (short*)take((size_t)IN_CH * 128 * 2);
  short* wt1s   = (short*)take((size_t)IN_CH * 128 * 2);
  short* wt2q   = (short*)take((size_t)HID_CH * 128 * 2);
  short* wt2k   = (short*)take((size_t)HID_CH * 128 * 2);
  short* wt2v   = (short*)take((size_t)HID_CH * 128 * 2);
  short* wt2s   = (short*)take((size_t)HID_CH * 128 * 2);
  float* pooled = (float*)take((size_t)N_GRAPHS * 128 * 4);

  const int* ei    = (const int*)d_in[1];   // int32 per harness contract
  const int* batch = (const int*)d_in[2];   // int32 per harness contract

  // A: zero + weight images
  prep<<<NB_SCAN + NB_CONV, 256, 0, stream>>>(
      (const float*)d_in[3], (const float*)d_in[5], (const float*)d_in[7], (const float*)d_in[9],
      (const float*)d_in[11], (const float*)d_in[13], (const float*)d_in[15], (const float*)d_in[17],
      (__hip_bfloat16*)wt1q, (__hip_bfloat16*)wt1k, (__hip_bfloat16*)wt1v, (__hip_bfloat16*)wt1s,
      (__hip_bfloat16*)wt2q, (__hip_bfloat16*)wt2k, (__hip_bfloat16*)wt2v, (__hip_bfloat16*)wt2s,
      cnt, tmp, pooled);

  // B: layer-1 QKVS gemm (blocks first) + degree count (backfill)
  count_gemm1<<<NB_GEMM + NB_CNT, 256, 0, stream>>>(
      ei, cnt, (const float*)d_in[0],
      wt1q, wt1k, wt1v, wt1s,
      (const float*)d_in[4], (const float*)d_in[6], (const float*)d_in[8], (const float*)d_in[10],
      Qb, KV8, Sb);

  // C: scan
  scan1<<<NB_SCAN, 256, 0, stream>>>(cnt, offs, bsum);
  scan2<<<1, 256, 0, stream>>>(bsum);

  // D: scatter
  scatter_edges<<<NB_CNT, 256, 0, stream>>>(ei, offs, bsum, tmp, ssrc);

  const int attn_grid = (N_NODES + 3) / 4;

  // E: layer-1 attention (writes H in place into Sb)
  attn_kernel<<<attn_grid, 256, 0, stream>>>(
      (const unsigned short*)Qb, KV8,
      (const unsigned short*)Sb, offs, bsum, ssrc, (unsigned short*)Sb);

  // F: layer-2 gemm (X = Sb, S in-place)
  gemm2<<<NB_GEMM, 256, 0, stream>>>(
      Sb, wt2q, wt2k, wt2v, wt2s,
      (const float*)d_in[12], (const float*)d_in[14], (const float*)d_in[16], (const float*)d_in[18],
      Qb, KV8, Sb);

  // G: layer-2 attention (writes H in place into Sb)
  attn_kernel<<<attn_grid, 256, 0, stream>>>(
      (const unsigned short*)Qb, KV8,
      (const unsigned short*)Sb, offs, bsum, ssrc, (unsigned short*)Sb);

  // Pool: 16 partials/graph -> one atomic per channel per partial, then final linear
  pool_partial<<<N_GRAPHS * 16, 128, 0, stream>>>(
      (const __hip_bfloat16*)Sb, batch, pooled);
  pool_final<<<N_GRAPHS, 128, 0, stream>>>(pooled, batch, (const float*)d_in[19],
                                           (const float*)d_in[20], (float*)d_out);
}

// Round 14
// 317.921 us; speedup vs baseline: 1.1667x; 1.1667x over previous
//
#include <hip/hip_runtime.h>
#include <hip/hip_bf16.h>
#include <cstdint>
#include <cstddef>

#define N_NODES 50000
#define N_EDGES 800000
#define IN_CH 64
#define HID_CH 128
#define N_GRAPHS 64

#define NB_SCAN ((N_NODES + 255) / 256)          // 196
#define NB_CNT  ((N_EDGES + 255) / 256)          // 3125
#define NB_GEMM ((N_NODES + 63) / 64)            // 782
#define W_ELEMS (4 * IN_CH * 128 + 4 * HID_CH * 128)  // 98304
#define NB_CONV ((W_ELEMS + 255) / 256)          // 384

typedef short s16x8 __attribute__((ext_vector_type(8)));
typedef float f32x4 __attribute__((ext_vector_type(4)));
typedef float f32x2 __attribute__((ext_vector_type(2)));

__device__ __forceinline__ float bf2f(__hip_bfloat16 v) { return __bfloat162float(v); }
__device__ __forceinline__ float bfbits2f(unsigned hs) {
  union { unsigned u; float f; } v; v.u = hs << 16; return v.f;
}
__device__ __forceinline__ float bfhi2f(unsigned w) {
  union { unsigned u; float f; } v; v.u = w & 0xffff0000u; return v.f;
}
__device__ __forceinline__ short f2bfs(float f) {
  __hip_bfloat16 h = __float2bfloat16(f); return *(short*)&h;
}
__device__ __forceinline__ unsigned short f2bfu(float f) {
  __hip_bfloat16 h = __float2bfloat16(f); return *(unsigned short*)&h;
}
__device__ __forceinline__ int clamp_id(int v) {
  if (v < 0) v = 0;
  if (v >= N_NODES) v = N_NODES - 1;
  return v;
}

// fp8 e4m3 (OCP) pack/unpack via gfx950 HW converters (word-selects are immediates).
__device__ __forceinline__ unsigned char f2fp8(float v) {
  return (unsigned char)(__builtin_amdgcn_cvt_pk_fp8_f32(v, v, 0, false) & 0xff);
}
template<bool HI>
__device__ __forceinline__ f32x2 fp8pair(unsigned w) {
  return __builtin_amdgcn_cvt_pk_f32_fp8(w, HI);
}

// ---------------- A: zero workspace + weight canonicalization ----------------
// W logical [KD][128] fp32 -> image WT[((k>>3)*128 + c)*8 + (k&7)] bf16
__global__ __launch_bounds__(256)
void prep(const float* __restrict__ w1q, const float* __restrict__ w1k,
          const float* __restrict__ w1v, const float* __restrict__ w1s,
          const float* __restrict__ w2q, const float* __restrict__ w2k,
          const float* __restrict__ w2v, const float* __restrict__ w2s,
          __hip_bfloat16* d1q, __hip_bfloat16* d1k, __hip_bfloat16* d1v, __hip_bfloat16* d1s,
          __hip_bfloat16* d2q, __hip_bfloat16* d2k, __hip_bfloat16* d2v, __hip_bfloat16* d2s,
          int* cnt, int* tmp, float* pooled)
{
  int bx = blockIdx.x;
  if (bx < NB_SCAN) {
    int i = bx * 256 + threadIdx.x;
    if (i < N_NODES) { cnt[i] = 0; tmp[i] = 0; }
    if (i < N_GRAPHS * HID_CH) pooled[i] = 0.f;
    return;
  }
  int j = (bx - NB_SCAN) * 256 + threadIdx.x;
  if (j >= W_ELEMS) return;
  const float* S[8] = {w1q, w1k, w1v, w1s, w2q, w2k, w2v, w2s};
  __hip_bfloat16* D[8] = {d1q, d1k, d1v, d1s, d2q, d2k, d2v, d2s};
  int m, r;
  if (j < 4 * IN_CH * 128) { m = j >> 13; r = j & 8191; }
  else { int jj = j - 4 * IN_CH * 128; m = 4 + (jj >> 14); r = jj & 16383; }
  int k = r >> 7, c = r & 127;
  D[m][(((k >> 3) * 128 + c) << 3) + (k & 7)] = __float2bfloat16(S[m][r]);
}

// ---------------- shared gemm body (R12-verified: direct global->LDS staging) ----------------
// Outputs: mat0=Q (bf16, row 128), mat1=K -> KV8 row byte [0..128), mat2=V -> KV8 [128..256),
// mat3=S (bf16, row 128). KV8 row = 256 bytes, fp8 e4m3.
// So may alias X (in-place per-row: A-frags register-resident before stores).
// NOTE: staging deliberately reads-and-immediately-writes (short live range) — the
// R13 register-pipelined variant spilled to scratch (+98 MB HBM traffic, -38 µs).
template<int KD, int XF32>
__device__ __forceinline__ void gemm_body(
    int bg, const void* X,
    const short* __restrict__ WTq, const short* __restrict__ WTk,
    const short* __restrict__ WTv, const short* __restrict__ WTs,
    const float* __restrict__ bq, const float* __restrict__ bk,
    const float* __restrict__ bv, const float* __restrict__ bs,
    short* Qo, unsigned char* KV8, short* So, short* lds)
{
  constexpr int KT = KD / 32;
  constexpr int CHUNKS = KD * 16;
  const int tid  = threadIdx.x;
  const int wid  = tid >> 6;
  const int lane = tid & 63;
  const int quad = lane >> 4;
  const int mm   = lane & 15;
  const int rt   = wid & 1;
  const int ch   = wid >> 1;
  const int rowbase = bg * 64 + rt * 32;

  s16x8 afrag[2][KT];
  #pragma unroll
  for (int t = 0; t < 2; ++t) {
    const int arow = rowbase + t * 16 + mm;
    if (arow < N_NODES) {
      if (XF32) {
        const float* xp = (const float*)X + (size_t)arow * KD;
        #pragma unroll
        for (int kt = 0; kt < KT; ++kt) {
          const float4* p = (const float4*)(xp + kt * 32 + quad * 8);
          float4 a = p[0], b = p[1];
          s16x8 fr;
          fr[0] = f2bfs(a.x); fr[1] = f2bfs(a.y); fr[2] = f2bfs(a.z); fr[3] = f2bfs(a.w);
          fr[4] = f2bfs(b.x); fr[5] = f2bfs(b.y); fr[6] = f2bfs(b.z); fr[7] = f2bfs(b.w);
          afrag[t][kt] = fr;
        }
      } else {
        const short* xp = (const short*)X + (size_t)arow * KD;
        #pragma unroll
        for (int kt = 0; kt < KT; ++kt)
          afrag[t][kt] = *(const s16x8*)(xp + kt * 32 + quad * 8);
      }
    } else {
      #pragma unroll
      for (int kt = 0; kt < KT; ++kt)
        afrag[t][kt] = (s16x8){0,0,0,0,0,0,0,0};
    }
  }

  const short* wts[4] = {WTq, WTk, WTv, WTs};
  const float* bias[4] = {bq, bk, bv, bs};

  #pragma unroll
  for (int mat = 0; mat < 4; ++mat) {
    if (mat > 0) __syncthreads();
    {
      const uint4* src = (const uint4*)wts[mat];
      uint4* dst = (uint4*)lds;
      #pragma unroll
      for (int i = 0; i < CHUNKS / 256; ++i)
        dst[tid + i * 256] = src[tid + i * 256];
    }
    __syncthreads();

    f32x4 acc[4][2];
    #pragma unroll
    for (int c4 = 0; c4 < 4; ++c4) {
      float b = bias[mat][ch * 64 + c4 * 16 + mm];
      f32x4 av = {b, b, b, b};
      acc[c4][0] = av; acc[c4][1] = av;
    }
    #pragma unroll
    for (int kt = 0; kt < KT; ++kt) {
      #pragma unroll
      for (int c4 = 0; c4 < 4; ++c4) {
        s16x8 bfrag = *(const s16x8*)(lds + ((((kt * 4 + quad) << 7) + ch * 64 + c4 * 16 + mm) << 3));
        acc[c4][0] = __builtin_amdgcn_mfma_f32_16x16x32_bf16(afrag[0][kt], bfrag, acc[c4][0], 0, 0, 0);
        acc[c4][1] = __builtin_amdgcn_mfma_f32_16x16x32_bf16(afrag[1][kt], bfrag, acc[c4][1], 0, 0, 0);
      }
    }
    if (mat == 1 || mat == 2) {
      unsigned char* O8 = KV8 + ((mat == 1) ? 0 : 128);
      #pragma unroll
      for (int c4 = 0; c4 < 4; ++c4) {
        const int col = ch * 64 + c4 * 16 + mm;
        #pragma unroll
        for (int t = 0; t < 2; ++t) {
          #pragma unroll
          for (int r = 0; r < 4; ++r) {
            int row = rowbase + t * 16 + quad * 4 + r;
            if (row < N_NODES)
              O8[(size_t)row * 256 + col] = f2fp8(acc[c4][t][r]);
          }
        }
      }
    } else {
      short* O = (mat == 0) ? Qo : So;
      #pragma unroll
      for (int c4 = 0; c4 < 4; ++c4) {
        const int col = ch * 64 + c4 * 16 + mm;
        #pragma unroll
        for (int t = 0; t < 2; ++t) {
          #pragma unroll
          for (int r = 0; r < 4; ++r) {
            int row = rowbase + t * 16 + quad * 4 + r;
            if (row < N_NODES)
              ((__hip_bfloat16*)O)[(size_t)row * 128 + col] = __float2bfloat16(acc[c4][t][r]);
          }
        }
      }
    }
  }
}

// ---------------- B: layer-1 gemm FIRST + count_deg after (LPT scheduling) ----------------
__global__ __launch_bounds__(256)
void count_gemm1(const int* __restrict__ ei, int* __restrict__ cnt,
                 const float* __restrict__ X,
                 const short* __restrict__ w1q, const short* __restrict__ w1k,
                 const short* __restrict__ w1v, const short* __restrict__ w1s,
                 const float* __restrict__ b1q, const float* __restrict__ b1k,
                 const float* __restrict__ b1v, const float* __restrict__ b1s,
                 short* Qb, unsigned char* KV8, short* Sb)
{
  __shared__ short lds[IN_CH * 128];   // 16 KB
  int bx = blockIdx.x;
  if (bx >= NB_GEMM) {
    int e = (bx - NB_GEMM) * 256 + threadIdx.x;
    if (e < N_EDGES) atomicAdd(&cnt[clamp_id(ei[N_EDGES + e])], 1);
    return;
  }
  gemm_body<IN_CH, 1>(bx, X, w1q, w1k, w1v, w1s, b1q, b1k, b1v, b1s,
                      Qb, KV8, Sb, lds);
}

// ---------------- C1/C2: scan ----------------
__global__ __launch_bounds__(256)
void scan1(const int* __restrict__ cnt, int* __restrict__ offs, int* __restrict__ bsum) {
  __shared__ int wsum[4];
  int t = threadIdx.x, lane = t & 63, w = t >> 6;
  int i = blockIdx.x * 256 + t;
  int v = (i < N_NODES) ? cnt[i] : 0;
  int x = v;
  #pragma unroll
  for (int o = 1; o < 64; o <<= 1) { int y = __shfl_up(x, o, 64); if (lane >= o) x += y; }
  if (lane == 63) wsum[w] = x;
  __syncthreads();
  if (t == 0) {
    int run = 0;
    #pragma unroll
    for (int k = 0; k < 4; ++k) { int tv = wsum[k]; wsum[k] = run; run += tv; }
    bsum[blockIdx.x] = run;
  }
  __syncthreads();
  if (i <= N_NODES) offs[i] = wsum[w] + x - v;   // block-local exclusive prefix
}

__global__ __launch_bounds__(256)
void scan2(int* __restrict__ bsum) {
  __shared__ int wsum[4];
  int t = threadIdx.x, lane = t & 63, w = t >> 6;
  int v = (t < NB_SCAN) ? bsum[t] : 0;
  int x = v;
  #pragma unroll
  for (int o = 1; o < 64; o <<= 1) { int y = __shfl_up(x, o, 64); if (lane >= o) x += y; }
  if (lane == 63) wsum[w] = x;
  __syncthreads();
  if (t == 0) {
    int run = 0;
    #pragma unroll
    for (int k = 0; k < 4; ++k) { int tv = wsum[k]; wsum[k] = run; run += tv; }
  }
  __syncthreads();
  if (t < NB_SCAN) bsum[t] = wsum[w] + x - v;    // exclusive prefix of block sums
}

// ---------------- D: scatter (global offset = offs[dst] + bsum[dst>>8]) ----------------
__global__ void scatter_edges(const int* __restrict__ ei, const int* __restrict__ offs,
                              const int* __restrict__ bsum,
                              int* __restrict__ tmp, int* __restrict__ ssrc) {
  int e = blockIdx.x * blockDim.x + threadIdx.x;
  if (e < N_EDGES) {
    int src = clamp_id(ei[e]);
    int dst = clamp_id(ei[N_EDGES + e]);
    int pos = offs[dst] + bsum[dst >> 8] + atomicAdd(&tmp[dst], 1);
    ssrc[pos] = src;
  }
}

// ---------------- attention (fp8 K/V, interleaved 256B rows) ----------------
// 1 wave per dst (4 dsts/block); 4 edge slots x 16 channel-lanes; quad=head.
// No-max softmax in exp2 domain; 1-deep K/V register prefetch.
// H may alias S (in-place per dst row).
__global__ __launch_bounds__(256)
void attn_kernel(const unsigned short* __restrict__ Q, const unsigned char* __restrict__ KV8,
                 const unsigned short* S,
                 const int* __restrict__ offs, const int* __restrict__ bsum,
                 const int* __restrict__ ssrc, unsigned short* H)
{
  const int dst = blockIdx.x * 4 + (threadIdx.x >> 6);
  if (dst >= N_NODES) return;               // wave-uniform
  const int lane = threadIdx.x & 63;
  const int sub  = lane >> 4;
  const int cl   = lane & 15;

  const float qs = 0.17677669529663687f * 1.4426950408889634f;  // 1/sqrt(32)*log2(e)
  uint4 qw = *(const uint4*)(Q + (size_t)dst * 128 + cl * 8);
  float q[8], a[8];
  #pragma unroll
  for (int i = 0; i < 4; ++i) {
    unsigned w = ((unsigned*)&qw)[i];
    q[2 * i]     = bfbits2f(w & 0xffffu) * qs;
    q[2 * i + 1] = bfhi2f(w) * qs;
    a[2 * i] = 0.f; a[2 * i + 1] = 0.f;
  }
  float s = 0.f;

  const int e0 = offs[dst] + bsum[dst >> 8];
  const int e1 = offs[dst + 1] + bsum[(dst + 1) >> 8];
  const int iters = (e1 - e0 + 3) >> 2;

  if (iters > 0) {
    int e = e0 + sub;
    bool have = (e < e1);
    int src = have ? ssrc[e] : ssrc[e0];
    float ph = have ? 1.f : 0.f;
    const unsigned char* kvp = KV8 + (size_t)src * 256 + cl * 8;
    uint2 kw = *(const uint2*)(kvp);
    uint2 vw = *(const uint2*)(kvp + 128);

    for (int it = 0; it < iters; ++it) {
      uint2 kwn, vwn;
      int en = e + 4;
      bool haven = (en < e1);
      float phn = haven ? 1.f : 0.f;
      if (it + 1 < iters) {                 // wave-uniform
        int srcn = haven ? ssrc[en] : ssrc[e0];
        const unsigned char* kvn = KV8 + (size_t)srcn * 256 + cl * 8;
        kwn = *(const uint2*)(kvn);
        vwn = *(const uint2*)(kvn + 128);
      } else {
        kwn = kw; vwn = vw;
      }
      f32x2 k0 = fp8pair<false>(kw.x), k1 = fp8pair<true>(kw.x);
      f32x2 k2 = fp8pair<false>(kw.y), k3 = fp8pair<true>(kw.y);
      float d = q[0] * k0.x + q[1] * k0.y + q[2] * k1.x + q[3] * k1.y
              + q[4] * k2.x + q[5] * k2.y + q[6] * k3.x + q[7] * k3.y;
      d += __shfl_xor(d, 1, 64);
      d += __shfl_xor(d, 2, 64);
      float p = exp2f(d) * ph;
      s += p;
      f32x2 v0 = fp8pair<false>(vw.x), v1 = fp8pair<true>(vw.x);
      f32x2 v2 = fp8pair<false>(vw.y), v3 = fp8pair<true>(vw.y);
      a[0] += p * v0.x; a[1] += p * v0.y;
      a[2] += p * v1.x; a[3] += p * v1.y;
      a[4] += p * v2.x; a[5] += p * v2.y;
      a[6] += p * v3.x; a[7] += p * v3.y;
      kw = kwn; vw = vwn; ph = phn; e = en;
    }
  }

  s += __shfl_xor(s, 16, 64);
  s += __shfl_xor(s, 32, 64);
  #pragma unroll
  for (int i = 0; i < 8; ++i) {
    a[i] += __shfl_xor(a[i], 16, 64);
    a[i] += __shfl_xor(a[i], 32, 64);
  }
  const float inv = (s > 0.f) ? (1.0f / s) : 0.f;

  if (sub == 0) {
    uint4 sw = *(const uint4*)(S + (size_t)dst * 128 + cl * 8);
    uint4 ow;
    #pragma unroll
    for (int i = 0; i < 4; ++i) {
      unsigned w = ((unsigned*)&sw)[i];
      float o0 = fmaxf(a[2 * i] * inv     + bfbits2f(w & 0xffffu), 0.f);
      float o1 = fmaxf(a[2 * i + 1] * inv + bfhi2f(w), 0.f);
      ((unsigned*)&ow)[i] = (unsigned)f2bfu(o0) | ((unsigned)f2bfu(o1) << 16);
    }
    *(uint4*)(H + (size_t)dst * 128 + cl * 8) = ow;
  }
}

// ---------------- F: layer-2 gemm ----------------
__global__ __launch_bounds__(256)
void gemm2(const short* __restrict__ X,
           const short* __restrict__ w2q, const short* __restrict__ w2k,
           const short* __restrict__ w2v, const short* __restrict__ w2s,
           const float* __restrict__ b2q, const float* __restrict__ b2k,
           const float* __restrict__ b2v, const float* __restrict__ b2s,
           short* Qb, unsigned char* KV8, short* Sb)
{
  __shared__ short lds[HID_CH * 128];  // 32 KB
  gemm_body<HID_CH, 0>(blockIdx.x, X, w2q, w2k, w2v, w2s, b2q, b2k, b2v, b2s,
                       Qb, KV8, Sb, lds);
}

// ---------------- pooling (R6-verified: 16 partials/graph, few atomics) ----------------
__device__ __forceinline__ int lower_bound_i(const int* __restrict__ b, int n, int val) {
  int lo = 0, hi = n;
  while (lo < hi) { int mid = (lo + hi) >> 1; if (b[mid] < val) lo = mid + 1; else hi = mid; }
  return lo;
}

__global__ __launch_bounds__(128)
void pool_partial(const __hip_bfloat16* __restrict__ H, const int* __restrict__ batch,
                  float* __restrict__ pooled)
{
  const int g = blockIdx.x >> 4, p = blockIdx.x & 15, t = threadIdx.x;
  const int s = lower_bound_i(batch, N_NODES, g);
  const int e = lower_bound_i(batch, N_NODES, g + 1);
  const int len = e - s;
  if (len <= 0) return;
  const int chunk = (len + 15) >> 4;
  const int a = s + p * chunk;
  const int b = min(a + chunk, e);
  if (a >= b) return;
  float sum = 0.f;
  for (int i = a; i < b; ++i) sum += bf2f(H[(size_t)i * 128 + t]);
  atomicAdd(&pooled[g * 128 + t], sum);
}

__global__ __launch_bounds__(128)
void pool_final(const float* __restrict__ pooled, const int* __restrict__ batch,
                const float* __restrict__ Wl, const float* __restrict__ bl,
                float* __restrict__ out)
{
  const int g = blockIdx.x, t = threadIdx.x;
  __shared__ float r0[128], r1[128];
  const int s = lower_bound_i(batch, N_NODES, g);
  const int e = lower_bound_i(batch, N_NODES, g + 1);
  const float inv = 1.0f / (float)max(e - s, 1);
  const float pc = pooled[g * 128 + t] * inv;
  r0[t] = pc * Wl[t * 2 + 0];
  r1[t] = pc * Wl[t * 2 + 1];
  __syncthreads();
  for (int o = 64; o > 0; o >>= 1) {
    if (t < o) { r0[t] += r0[t + o]; r1[t] += r1[t + o]; }
    __syncthreads();
  }
  if (t == 0) {
    out[g * 2 + 0] = r0[0] + bl[0];
    out[g * 2 + 1] = r1[0] + bl[1];
  }
}

// ---------------- launch ----------------

extern "C" void kernel_launch(void* const* d_in, const int* in_sizes, int n_in,
                              void* d_out, int out_size, void* d_ws, size_t ws_size,
                              hipStream_t stream) {
  uintptr_t base = (uintptr_t)d_ws;
  auto take = [&](size_t bytes) -> uintptr_t {
    uintptr_t p = base;
    base += (bytes + 255) & ~(size_t)255;
    return p;
  };

  int*   cnt    = (int*)take((size_t)N_NODES * 4);
  int*   tmp    = (int*)take((size_t)N_NODES * 4);
  int*   offs   = (int*)take((size_t)(N_NODES + 1) * 4);
  int*   bsum   = (int*)take((size_t)NB_SCAN * 4);
  int*   ssrc   = (int*)take((size_t)N_EDGES * 4);
  short* Qb     = (short*)take((size_t)N_NODES * 128 * 2);
  unsigned char* KV8 = (unsigned char*)take((size_t)N_NODES * 256);  // fp8 [K|V] rows
  short* Sb     = (short*)take((size_t)N_NODES * 128 * 2);  // S / H / layer-2 X (in-place)
  short* wt1q   = (short*)take((size_t)IN_CH * 128 * 2);
  short* wt1k   = (short*)take((size_t)IN_CH * 128 * 2);
  short* wt1v   = (short*)take((size_t)IN_CH * 128 * 2);
  short* wt1s   = (short*)take((size_t)IN_CH * 128 * 2);
  short* wt2q   = (short*)take((size_t)HID_CH * 128 * 2);
  short* wt2k   = (short*)take((size_t)HID_CH * 128 * 2);
  short* wt2v   = (short*)take((size_t)HID_CH * 128 * 2);
  short* wt2s   = (short*)take((size_t)HID_CH * 128 * 2);
  float* pooled = (float*)take((size_t)N_GRAPHS * 128 * 4);

  const int* ei    = (const int*)d_in[1];   // int32 per harness contract
  const int* batch = (const int*)d_in[2];   // int32 per harness contract

  // A: zero + weight images
  prep<<<NB_SCAN + NB_CONV, 256, 0, stream>>>(
      (const float*)d_in[3], (const float*)d_in[5], (const float*)d_in[7], (const float*)d_in[9],
      (const float*)d_in[11], (const float*)d_in[13], (const float*)d_in[15], (const float*)d_in[17],
      (__hip_bfloat16*)wt1q, (__hip_bfloat16*)wt1k, (__hip_bfloat16*)wt1v, (__hip_bfloat16*)wt1s,
      (__hip_bfloat16*)wt2q, (__hip_bfloat16*)wt2k, (__hip_bfloat16*)wt2v, (__hip_bfloat16*)wt2s,
      cnt, tmp, pooled);

  // B: layer-1 QKVS gemm (blocks first) + degree count (backfill)
  count_gemm1<<<NB_GEMM + NB_CNT, 256, 0, stream>>>(
      ei, cnt, (const float*)d_in[0],
      wt1q, wt1k, wt1v, wt1s,
      (const float*)d_in[4], (const float*)d_in[6], (const float*)d_in[8], (const float*)d_in[10],
      Qb, KV8, Sb);

  // C: scan
  scan1<<<NB_SCAN, 256, 0, stream>>>(cnt, offs, bsum);
  scan2<<<1, 256, 0, stream>>>(bsum);

  // D: scatter
  scatter_edges<<<NB_CNT, 256, 0, stream>>>(ei, offs, bsum, tmp, ssrc);

  const int attn_grid = (N_NODES + 3) / 4;

  // E: layer-1 attention (writes H in place into Sb)
  attn_kernel<<<attn_grid, 256, 0, stream>>>(
      (const unsigned short*)Qb, KV8,
      (const unsigned short*)Sb, offs, bsum, ssrc, (unsigned short*)Sb);

  // F: layer-2 gemm (X = Sb, S in-place)
  gemm2<<<NB_GEMM, 256, 0, stream>>>(
      Sb, wt2q, wt2k, wt2v, wt2s,
      (const float*)d_in[12], (const float*)d_in[14], (const float*)d_in[16], (const float*)d_in[18],
      Qb, KV8, Sb);

  // G: layer-2 attention (writes H in place into Sb)
  attn_kernel<<<attn_grid, 256, 0, stream>>>(
      (const unsigned short*)Qb, KV8,
      (const unsigned short*)Sb, offs, bsum, ssrc, (unsigned short*)Sb);

  // Pool: 16 partials/graph -> one atomic per channel per partial, then final linear
  pool_partial<<<N_GRAPHS * 16, 128, 0, stream>>>(
      (const __hip_bfloat16*)Sb, batch, pooled);
  pool_final<<<N_GRAPHS, 128, 0, stream>>>(pooled, batch, (const float*)d_in[19],
                                           (const float*)d_in[20], (float*)d_out);
}

// Round 16
// 317.775 us; speedup vs baseline: 1.1673x; 1.0005x over previous
//
#include <hip/hip_runtime.h>
#include <hip/hip_bf16.h>
#include <cstdint>
#include <cstddef>

#define N_NODES 50000
#define N_EDGES 800000
#define IN_CH 64
#define HID_CH 128
#define N_GRAPHS 64

#define NB_SCAN ((N_NODES + 255) / 256)          // 196
#define NB_CNT  ((N_EDGES + 255) / 256)          // 3125
#define NB_GEMM ((N_NODES + 63) / 64)            // 782
#define W_ELEMS (4 * IN_CH * 128 + 4 * HID_CH * 128)  // 98304
#define NB_CONV ((W_ELEMS + 255) / 256)          // 384

typedef short s16x8 __attribute__((ext_vector_type(8)));
typedef float f32x4 __attribute__((ext_vector_type(4)));
typedef float f32x2 __attribute__((ext_vector_type(2)));

__device__ __forceinline__ float bf2f(__hip_bfloat16 v) { return __bfloat162float(v); }
__device__ __forceinline__ float bfbits2f(unsigned hs) {
  union { unsigned u; float f; } v; v.u = hs << 16; return v.f;
}
__device__ __forceinline__ float bfhi2f(unsigned w) {
  union { unsigned u; float f; } v; v.u = w & 0xffff0000u; return v.f;
}
__device__ __forceinline__ short f2bfs(float f) {
  __hip_bfloat16 h = __float2bfloat16(f); return *(short*)&h;
}
__device__ __forceinline__ unsigned short f2bfu(float f) {
  __hip_bfloat16 h = __float2bfloat16(f); return *(unsigned short*)&h;
}
__device__ __forceinline__ int clamp_id(int v) {
  if (v < 0) v = 0;
  if (v >= N_NODES) v = N_NODES - 1;
  return v;
}

// fp8 e4m3 (OCP) pack/unpack via gfx950 HW converters (word-selects are immediates).
__device__ __forceinline__ unsigned char f2fp8(float v) {
  return (unsigned char)(__builtin_amdgcn_cvt_pk_fp8_f32(v, v, 0, false) & 0xff);
}
template<bool HI>
__device__ __forceinline__ f32x2 fp8pair(unsigned w) {
  return __builtin_amdgcn_cvt_pk_f32_fp8(w, HI);
}

// ---------------- A: zero workspace + weight canonicalization ----------------
// (count_deg must NOT be fused here: zeroing of cnt races the atomics — R15 failure.)
__global__ __launch_bounds__(256)
void prep(const float* __restrict__ w1q, const float* __restrict__ w1k,
          const float* __restrict__ w1v, const float* __restrict__ w1s,
          const float* __restrict__ w2q, const float* __restrict__ w2k,
          const float* __restrict__ w2v, const float* __restrict__ w2s,
          __hip_bfloat16* d1q, __hip_bfloat16* d1k, __hip_bfloat16* d1v, __hip_bfloat16* d1s,
          __hip_bfloat16* d2q, __hip_bfloat16* d2k, __hip_bfloat16* d2v, __hip_bfloat16* d2s,
          int* cnt, int* tmp, float* pooled)
{
  int bx = blockIdx.x;
  if (bx < NB_SCAN) {
    int i = bx * 256 + threadIdx.x;
    if (i < N_NODES) { cnt[i] = 0; tmp[i] = 0; }
    if (i < N_GRAPHS * HID_CH) pooled[i] = 0.f;
    return;
  }
  int j = (bx - NB_SCAN) * 256 + threadIdx.x;
  if (j >= W_ELEMS) return;
  const float* S[8] = {w1q, w1k, w1v, w1s, w2q, w2k, w2v, w2s};
  __hip_bfloat16* D[8] = {d1q, d1k, d1v, d1s, d2q, d2k, d2v, d2s};
  int m, r;
  if (j < 4 * IN_CH * 128) { m = j >> 13; r = j & 8191; }
  else { int jj = j - 4 * IN_CH * 128; m = 4 + (jj >> 14); r = jj & 16383; }
  int k = r >> 7, c = r & 127;
  D[m][(((k >> 3) * 128 + c) << 3) + (k & 7)] = __float2bfloat16(S[m][r]);
}

// ---------------- B: degree count (own dispatch — after prep's zeroing) ----------------
__global__ void count_deg(const int* __restrict__ ei, int* __restrict__ cnt) {
  int e = blockIdx.x * blockDim.x + threadIdx.x;
  if (e < N_EDGES) atomicAdd(&cnt[clamp_id(ei[N_EDGES + e])], 1);
}

// ---------------- shared gemm body (R12/R14-verified: direct global->LDS staging) ----------------
// Outputs: mat0=Q (bf16, row 128), mat1=K -> KV8 row byte [0..128), mat2=V -> KV8 [128..256),
// mat3=S (bf16, row 128). KV8 row = 256 bytes, fp8 e4m3.
// So may alias X (in-place per-row: A-frags register-resident before stores).
template<int KD, int XF32>
__device__ __forceinline__ void gemm_body(
    int bg, const void* X,
    const short* __restrict__ WTq, const short* __restrict__ WTk,
    const short* __restrict__ WTv, const short* __restrict__ WTs,
    const float* __restrict__ bq, const float* __restrict__ bk,
    const float* __restrict__ bv, const float* __restrict__ bs,
    short* Qo, unsigned char* KV8, short* So, short* lds)
{
  constexpr int KT = KD / 32;
  constexpr int CHUNKS = KD * 16;
  const int tid  = threadIdx.x;
  const int wid  = tid >> 6;
  const int lane = tid & 63;
  const int quad = lane >> 4;
  const int mm   = lane & 15;
  const int rt   = wid & 1;
  const int ch   = wid >> 1;
  const int rowbase = bg * 64 + rt * 32;

  s16x8 afrag[2][KT];
  #pragma unroll
  for (int t = 0; t < 2; ++t) {
    const int arow = rowbase + t * 16 + mm;
    if (arow < N_NODES) {
      if (XF32) {
        const float* xp = (const float*)X + (size_t)arow * KD;
        #pragma unroll
        for (int kt = 0; kt < KT; ++kt) {
          const float4* p = (const float4*)(xp + kt * 32 + quad * 8);
          float4 a = p[0], b = p[1];
          s16x8 fr;
          fr[0] = f2bfs(a.x); fr[1] = f2bfs(a.y); fr[2] = f2bfs(a.z); fr[3] = f2bfs(a.w);
          fr[4] = f2bfs(b.x); fr[5] = f2bfs(b.y); fr[6] = f2bfs(b.z); fr[7] = f2bfs(b.w);
          afrag[t][kt] = fr;
        }
      } else {
        const short* xp = (const short*)X + (size_t)arow * KD;
        #pragma unroll
        for (int kt = 0; kt < KT; ++kt)
          afrag[t][kt] = *(const s16x8*)(xp + kt * 32 + quad * 8);
      }
    } else {
      #pragma unroll
      for (int kt = 0; kt < KT; ++kt)
        afrag[t][kt] = (s16x8){0,0,0,0,0,0,0,0};
    }
  }

  const short* wts[4] = {WTq, WTk, WTv, WTs};
  const float* bias[4] = {bq, bk, bv, bs};

  #pragma unroll
  for (int mat = 0; mat < 4; ++mat) {
    if (mat > 0) __syncthreads();
    {
      const uint4* src = (const uint4*)wts[mat];
      uint4* dst = (uint4*)lds;
      #pragma unroll
      for (int i = 0; i < CHUNKS / 256; ++i)
        dst[tid + i * 256] = src[tid + i * 256];
    }
    __syncthreads();

    f32x4 acc[4][2];
    #pragma unroll
    for (int c4 = 0; c4 < 4; ++c4) {
      float b = bias[mat][ch * 64 + c4 * 16 + mm];
      f32x4 av = {b, b, b, b};
      acc[c4][0] = av; acc[c4][1] = av;
    }
    #pragma unroll
    for (int kt = 0; kt < KT; ++kt) {
      #pragma unroll
      for (int c4 = 0; c4 < 4; ++c4) {
        s16x8 bfrag = *(const s16x8*)(lds + ((((kt * 4 + quad) << 7) + ch * 64 + c4 * 16 + mm) << 3));
        acc[c4][0] = __builtin_amdgcn_mfma_f32_16x16x32_bf16(afrag[0][kt], bfrag, acc[c4][0], 0, 0, 0);
        acc[c4][1] = __builtin_amdgcn_mfma_f32_16x16x32_bf16(afrag[1][kt], bfrag, acc[c4][1], 0, 0, 0);
      }
    }
    if (mat == 1 || mat == 2) {
      unsigned char* O8 = KV8 + ((mat == 1) ? 0 : 128);
      #pragma unroll
      for (int c4 = 0; c4 < 4; ++c4) {
        const int col = ch * 64 + c4 * 16 + mm;
        #pragma unroll
        for (int t = 0; t < 2; ++t) {
          #pragma unroll
          for (int r = 0; r < 4; ++r) {
            int row = rowbase + t * 16 + quad * 4 + r;
            if (row < N_NODES)
              O8[(size_t)row * 256 + col] = f2fp8(acc[c4][t][r]);
          }
        }
      }
    } else {
      short* O = (mat == 0) ? Qo : So;
      #pragma unroll
      for (int c4 = 0; c4 < 4; ++c4) {
        const int col = ch * 64 + c4 * 16 + mm;
        #pragma unroll
        for (int t = 0; t < 2; ++t) {
          #pragma unroll
          for (int r = 0; r < 4; ++r) {
            int row = rowbase + t * 16 + quad * 4 + r;
            if (row < N_NODES)
              ((__hip_bfloat16*)O)[(size_t)row * 128 + col] = __float2bfloat16(acc[c4][t][r]);
          }
        }
      }
    }
  }
}

// ---------------- C1/C2: scan ----------------
__global__ __launch_bounds__(256)
void scan1(const int* __restrict__ cnt, int* __restrict__ offs, int* __restrict__ bsum) {
  __shared__ int wsum[4];
  int t = threadIdx.x, lane = t & 63, w = t >> 6;
  int i = blockIdx.x * 256 + t;
  int v = (i < N_NODES) ? cnt[i] : 0;
  int x = v;
  #pragma unroll
  for (int o = 1; o < 64; o <<= 1) { int y = __shfl_up(x, o, 64); if (lane >= o) x += y; }
  if (lane == 63) wsum[w] = x;
  __syncthreads();
  if (t == 0) {
    int run = 0;
    #pragma unroll
    for (int k = 0; k < 4; ++k) { int tv = wsum[k]; wsum[k] = run; run += tv; }
    bsum[blockIdx.x] = run;
  }
  __syncthreads();
  if (i <= N_NODES) offs[i] = wsum[w] + x - v;   // block-local exclusive prefix
}

__global__ __launch_bounds__(256)
void scan2(int* __restrict__ bsum) {
  __shared__ int wsum[4];
  int t = threadIdx.x, lane = t & 63, w = t >> 6;
  int v = (t < NB_SCAN) ? bsum[t] : 0;
  int x = v;
  #pragma unroll
  for (int o = 1; o < 64; o <<= 1) { int y = __shfl_up(x, o, 64); if (lane >= o) x += y; }
  if (lane == 63) wsum[w] = x;
  __syncthreads();
  if (t == 0) {
    int run = 0;
    #pragma unroll
    for (int k = 0; k < 4; ++k) { int tv = wsum[k]; wsum[k] = run; run += tv; }
  }
  __syncthreads();
  if (t < NB_SCAN) bsum[t] = wsum[w] + x - v;    // exclusive prefix of block sums
}

// ---------------- D: layer-1 gemm + edge scatter fused (independent, race-free:
// scatter deps (offs/bsum from scan, tmp zeroed in prep) all cross dispatch bounds) ----
__global__ __launch_bounds__(256)
void scatter_gemm1(const int* __restrict__ ei, const int* __restrict__ offs,
                   const int* __restrict__ bsum, int* __restrict__ tmp, int* __restrict__ ssrc,
                   const float* __restrict__ X,
                   const short* __restrict__ w1q, const short* __restrict__ w1k,
                   const short* __restrict__ w1v, const short* __restrict__ w1s,
                   const float* __restrict__ b1q, const float* __restrict__ b1k,
                   const float* __restrict__ b1v, const float* __restrict__ b1s,
                   short* Qb, unsigned char* KV8, short* Sb)
{
  __shared__ short lds[IN_CH * 128];   // 16 KB
  int bx = blockIdx.x;
  if (bx >= NB_GEMM) {
    int e = (bx - NB_GEMM) * 256 + threadIdx.x;
    if (e < N_EDGES) {
      int src = clamp_id(ei[e]);
      int dst = clamp_id(ei[N_EDGES + e]);
      int pos = offs[dst] + bsum[dst >> 8] + atomicAdd(&tmp[dst], 1);
      ssrc[pos] = src;
    }
    return;
  }
  gemm_body<IN_CH, 1>(bx, X, w1q, w1k, w1v, w1s, b1q, b1k, b1v, b1s,
                      Qb, KV8, Sb, lds);
}

// ---------------- attention (fp8 K/V, interleaved 256B rows) ----------------
// 1 wave per dst (4 dsts/block); 4 edge slots x 16 channel-lanes; quad=head.
// No-max softmax in exp2 domain; 1-deep K/V register prefetch.
// H may alias S (in-place per dst row).
__global__ __launch_bounds__(256)
void attn_kernel(const unsigned short* __restrict__ Q, const unsigned char* __restrict__ KV8,
                 const unsigned short* S,
                 const int* __restrict__ offs, const int* __restrict__ bsum,
                 const int* __restrict__ ssrc, unsigned short* H)
{
  const int dst = blockIdx.x * 4 + (threadIdx.x >> 6);
  if (dst >= N_NODES) return;               // wave-uniform
  const int lane = threadIdx.x & 63;
  const int sub  = lane >> 4;
  const int cl   = lane & 15;

  const float qs = 0.17677669529663687f * 1.4426950408889634f;  // 1/sqrt(32)*log2(e)
  uint4 qw = *(const uint4*)(Q + (size_t)dst * 128 + cl * 8);
  float q[8], a[8];
  #pragma unroll
  for (int i = 0; i < 4; ++i) {
    unsigned w = ((unsigned*)&qw)[i];
    q[2 * i]     = bfbits2f(w & 0xffffu) * qs;
    q[2 * i + 1] = bfhi2f(w) * qs;
    a[2 * i] = 0.f; a[2 * i + 1] = 0.f;
  }
  float s = 0.f;

  const int e0 = offs[dst] + bsum[dst >> 8];
  const int e1 = offs[dst + 1] + bsum[(dst + 1) >> 8];
  const int iters = (e1 - e0 + 3) >> 2;

  if (iters > 0) {
    int e = e0 + sub;
    bool have = (e < e1);
    int src = have ? ssrc[e] : ssrc[e0];
    float ph = have ? 1.f : 0.f;
    const unsigned char* kvp = KV8 + (size_t)src * 256 + cl * 8;
    uint2 kw = *(const uint2*)(kvp);
    uint2 vw = *(const uint2*)(kvp + 128);

    for (int it = 0; it < iters; ++it) {
      uint2 kwn, vwn;
      int en = e + 4;
      bool haven = (en < e1);
      float phn = haven ? 1.f : 0.f;
      if (it + 1 < iters) {                 // wave-uniform
        int srcn = haven ? ssrc[en] : ssrc[e0];
        const unsigned char* kvn = KV8 + (size_t)srcn * 256 + cl * 8;
        kwn = *(const uint2*)(kvn);
        vwn = *(const uint2*)(kvn + 128);
      } else {
        kwn = kw; vwn = vw;
      }
      f32x2 k0 = fp8pair<false>(kw.x), k1 = fp8pair<true>(kw.x);
      f32x2 k2 = fp8pair<false>(kw.y), k3 = fp8pair<true>(kw.y);
      float d = q[0] * k0.x + q[1] * k0.y + q[2] * k1.x + q[3] * k1.y
              + q[4] * k2.x + q[5] * k2.y + q[6] * k3.x + q[7] * k3.y;
      d += __shfl_xor(d, 1, 64);
      d += __shfl_xor(d, 2, 64);
      float p = exp2f(d) * ph;
      s += p;
      f32x2 v0 = fp8pair<false>(vw.x), v1 = fp8pair<true>(vw.x);
      f32x2 v2 = fp8pair<false>(vw.y), v3 = fp8pair<true>(vw.y);
      a[0] += p * v0.x; a[1] += p * v0.y;
      a[2] += p * v1.x; a[3] += p * v1.y;
      a[4] += p * v2.x; a[5] += p * v2.y;
      a[6] += p * v3.x; a[7] += p * v3.y;
      kw = kwn; vw = vwn; ph = phn; e = en;
    }
  }

  s += __shfl_xor(s, 16, 64);
  s += __shfl_xor(s, 32, 64);
  #pragma unroll
  for (int i = 0; i < 8; ++i) {
    a[i] += __shfl_xor(a[i], 16, 64);
    a[i] += __shfl_xor(a[i], 32, 64);
  }
  const float inv = (s > 0.f) ? (1.0f / s) : 0.f;

  if (sub == 0) {
    uint4 sw = *(const uint4*)(S + (size_t)dst * 128 + cl * 8);
    uint4 ow;
    #pragma unroll
    for (int i = 0; i < 4; ++i) {
      unsigned w = ((unsigned*)&sw)[i];
      float o0 = fmaxf(a[2 * i] * inv     + bfbits2f(w & 0xffffu), 0.f);
      float o1 = fmaxf(a[2 * i + 1] * inv + bfhi2f(w), 0.f);
      ((unsigned*)&ow)[i] = (unsigned)f2bfu(o0) | ((unsigned)f2bfu(o1) << 16);
    }
    *(uint4*)(H + (size_t)dst * 128 + cl * 8) = ow;
  }
}

// ---------------- F: layer-2 gemm ----------------
__global__ __launch_bounds__(256)
void gemm2(const short* __restrict__ X,
           const short* __restrict__ w2q, const short* __restrict__ w2k,
           const short* __restrict__ w2v, const short* __restrict__ w2s,
           const float* __restrict__ b2q, const float* __restrict__ b2k,
           const float* __restrict__ b2v, const float* __restrict__ b2s,
           short* Qb, unsigned char* KV8, short* Sb)
{
  __shared__ short lds[HID_CH * 128];  // 32 KB
  gemm_body<HID_CH, 0>(blockIdx.x, X, w2q, w2k, w2v, w2s, b2q, b2k, b2v, b2s,
                       Qb, KV8, Sb, lds);
}

// ---------------- pooling (R6-verified: 16 partials/graph, few atomics) ----------------
__device__ __forceinline__ int lower_bound_i(const int* __restrict__ b, int n, int val) {
  int lo = 0, hi = n;
  while (lo < hi) { int mid = (lo + hi) >> 1; if (b[mid] < val) lo = mid + 1; else hi = mid; }
  return lo;
}

__global__ __launch_bounds__(128)
void pool_partial(const __hip_bfloat16* __restrict__ H, const int* __restrict__ batch,
                  float* __restrict__ pooled)
{
  const int g = blockIdx.x >> 4, p = blockIdx.x & 15, t = threadIdx.x;
  const int s = lower_bound_i(batch, N_NODES, g);
  const int e = lower_bound_i(batch, N_NODES, g + 1);
  const int len = e - s;
  if (len <= 0) return;
  const int chunk = (len + 15) >> 4;
  const int a = s + p * chunk;
  const int b = min(a + chunk, e);
  if (a >= b) return;
  float sum = 0.f;
  for (int i = a; i < b; ++i) sum += bf2f(H[(size_t)i * 128 + t]);
  atomicAdd(&pooled[g * 128 + t], sum);
}

__global__ __launch_bounds__(128)
void pool_final(const float* __restrict__ pooled, const int* __restrict__ batch,
                const float* __restrict__ Wl, const float* __restrict__ bl,
                float* __restrict__ out)
{
  const int g = blockIdx.x, t = threadIdx.x;
  __shared__ float r0[128], r1[128];
  const int s = lower_bound_i(batch, N_NODES, g);
  const int e = lower_bound_i(batch, N_NODES, g + 1);
  const float inv = 1.0f / (float)max(e - s, 1);
  const float pc = pooled[g * 128 + t] * inv;
  r0[t] = pc * Wl[t * 2 + 0];
  r1[t] = pc * Wl[t * 2 + 1];
  __syncthreads();
  for (int o = 64; o > 0; o >>= 1) {
    if (t < o) { r0[t] += r0[t + o]; r1[t] += r1[t + o]; }
    __syncthreads();
  }
  if (t == 0) {
    out[g * 2 + 0] = r0[0] + bl[0];
    out[g * 2 + 1] = r1[0] + bl[1];
  }
}

// ---------------- launch ----------------

extern "C" void kernel_launch(void* const* d_in, const int* in_sizes, int n_in,
                              void* d_out, int out_size, void* d_ws, size_t ws_size,
                              hipStream_t stream) {
  uintptr_t base = (uintptr_t)d_ws;
  auto take = [&](size_t bytes) -> uintptr_t {
    uintptr_t p = base;
    base += (bytes + 255) & ~(size_t)255;
    return p;
  };

  int*   cnt    = (int*)take((size_t)N_NODES * 4);
  int*   tmp    = (int*)take((size_t)N_NODES * 4);
  int*   offs   = (int*)take((size_t)(N_NODES + 1) * 4);
  int*   bsum   = (int*)take((size_t)NB_SCAN * 4);
  int*   ssrc   = (int*)take((size_t)N_EDGES * 4);
  short* Qb     = (short*)take((size_t)N_NODES * 128 * 2);
  unsigned char* KV8 = (unsigned char*)take((size_t)N_NODES * 256);  // fp8 [K|V] rows
  short* Sb     = (short*)take((size_t)N_NODES * 128 * 2);  // S / H / layer-2 X (in-place)
  short* wt1q   = (short*)take((size_t)IN_CH * 128 * 2);
  short* wt1k   = (short*)take((size_t)IN_CH * 128 * 2);
  short* wt1v   = (short*)take((size_t)IN_CH * 128 * 2);
  short* wt1s   = (short*)take((size_t)IN_CH * 128 * 2);
  short* wt2q   = (short*)take((size_t)HID_CH * 128 * 2);
  short* wt2k   = (short*)take((size_t)HID_CH * 128 * 2);
  short* wt2v   = (short*)take((size_t)HID_CH * 128 * 2);
  short* wt2s   = (short*)take((size_t)HID_CH * 128 * 2);
  float* pooled = (float*)take((size_t)N_GRAPHS * 128 * 4);

  const int* ei    = (const int*)d_in[1];   // int32 per harness contract
  const int* batch = (const int*)d_in[2];   // int32 per harness contract

  // A: zero + weight images
  prep<<<NB_SCAN + NB_CONV, 256, 0, stream>>>(
      (const float*)d_in[3], (const float*)d_in[5], (const float*)d_in[7], (const float*)d_in[9],
      (const float*)d_in[11], (const float*)d_in[13], (const float*)d_in[15], (const float*)d_in[17],
      (__hip_bfloat16*)wt1q, (__hip_bfloat16*)wt1k, (__hip_bfloat16*)wt1v, (__hip_bfloat16*)wt1s,
      (__hip_bfloat16*)wt2q, (__hip_bfloat16*)wt2k, (__hip_bfloat16*)wt2v, (__hip_bfloat16*)wt2s,
      cnt, tmp, pooled);

  // B: degree count (race-free: after prep's zeroing via dispatch boundary)
  count_deg<<<NB_CNT, 256, 0, stream>>>(ei, cnt);

  // C: scan
  scan1<<<NB_SCAN, 256, 0, stream>>>(cnt, offs, bsum);
  scan2<<<1, 256, 0, stream>>>(bsum);

  // D: layer-1 QKVS gemm (blocks first) + edge scatter (backfill, independent)
  scatter_gemm1<<<NB_GEMM + NB_CNT, 256, 0, stream>>>(
      ei, offs, bsum, tmp, ssrc,
      (const float*)d_in[0],
      wt1q, wt1k, wt1v, wt1s,
      (const float*)d_in[4], (const float*)d_in[6], (const float*)d_in[8], (const float*)d_in[10],
      Qb, KV8, Sb);

  const int attn_grid = (N_NODES + 3) / 4;

  // E: layer-1 attention (writes H in place into Sb)
  attn_kernel<<<attn_grid, 256, 0, stream>>>(
      (const unsigned short*)Qb, KV8,
      (const unsigned short*)Sb, offs, bsum, ssrc, (unsigned short*)Sb);

  // F: layer-2 gemm (X = Sb, S in-place)
  gemm2<<<NB_GEMM, 256, 0, stream>>>(
      Sb, wt2q, wt2k, wt2v, wt2s,
      (const float*)d_in[12], (const float*)d_in[14], (const float*)d_in[16], (const float*)d_in[18],
      Qb, KV8, Sb);

  // G: layer-2 attention (writes H in place into Sb)
  attn_kernel<<<attn_grid, 256, 0, stream>>>(
      (const unsigned short*)Qb, KV8,
      (const unsigned short*)Sb, offs, bsum, ssrc, (unsigned short*)Sb);

  // Pool: 16 partials/graph -> one atomic per channel per partial, then final linear
  pool_partial<<<N_GRAPHS * 16, 128, 0, stream>>>(
      (const __hip_bfloat16*)Sb, batch, pooled);
  pool_final<<<N_GRAPHS, 128, 0, stream>>>(pooled, batch, (const float*)d_in[19],
                                           (const float*)d_in[20], (float*)d_out);
}